// Round 6
// baseline (629.153 us; speedup 1.0000x reference)
//
#include <hip/hip_runtime.h>

// ---------- bf16 helpers ----------
__device__ __forceinline__ float bf2f(unsigned short u){
    union { unsigned int i; float f; } v; v.i = ((unsigned int)u) << 16; return v.f;
}
__device__ __forceinline__ unsigned short f2bf(float f){
    union { unsigned int i; float f; } v; v.f = f;
    unsigned int i = v.i;
    unsigned int r = i + 0x7FFFu + ((i >> 16) & 1u);   // round-nearest-even
    return (unsigned short)(r >> 16);
}
__device__ __forceinline__ float sigm(float x){ return 1.0f / (1.0f + __expf(-x)); }

// flag-dispatched scalar load: fF=1 -> fp32, fF=0 -> bf16
__device__ __forceinline__ float ldsel(const void* p, size_t idx, int fF){
    float r;
    if (fF) r = ((const float*)p)[idx];
    else    r = bf2f(((const unsigned short*)p)[idx]);
    return r;
}

typedef __attribute__((ext_vector_type(8))) short s8v;   // 8 bf16 (4 VGPRs)
typedef __attribute__((ext_vector_type(4))) float f4v;   // 4 fp32 accum

// ---------------------------------------------------------------------------
// k_detect: flags[0]=1 if float tensors are fp32 (else bf16);
//           flags[1]=1 if edge_index is int64 (else int32).
__global__ void k_detect(const unsigned short* __restrict__ X,
                         const int* __restrict__ ei, int* __restrict__ flags){
    __shared__ int cnt, nz;
    if (threadIdx.x == 0){ cnt = 0; nz = 0; }
    __syncthreads();
    int ok = 0;
    for (int i = threadIdx.x; i < 2048; i += 256){
        int e = (X[i] >> 7) & 0xFF;
        if (e >= 96 && e <= 160) ok++;
    }
    atomicAdd(&cnt, ok);
    int nzl = 0;
    for (int i = threadIdx.x; i < 128; i += 256)
        if (ei[2*i + 1] != 0) nzl++;
    atomicAdd(&nz, nzl);
    __syncthreads();
    if (threadIdx.x == 0){
        flags[0] = (cnt < 1843) ? 1 : 0;   // <90% plausible-bf16 => fp32
        flags[1] = (nz == 0)   ? 1 : 0;    // all odd int32 words zero => int64
    }
}

// ---------------------------------------------------------------------------
struct PackArgs {
    const void* Wx[4];
    const void* Wh[4];
    const void* bx[4];
    const void* bh[4];
};

// k_fused1: block-range-partitioned independent preamble.
//  blocks [0,nbT):          tobf  — XHb[node][256] bf16 = [X row | H row]
//  blocks [nbT,nbT+nbC):    cnt   — off[e] = cnt[d]++ ; deg[d] += w
//  blocks [nbT+nbC, +512):  pack  — W -> MFMA B lane order; bias = bx+bh
__global__ void k_fused1(const void* __restrict__ X, const void* __restrict__ H,
                         unsigned int* __restrict__ XHb32,
                         const int* __restrict__ ei, const void* __restrict__ ew,
                         int* __restrict__ cnt, float* __restrict__ deg,
                         int* __restrict__ off,
                         PackArgs pa, unsigned short* __restrict__ Bp,
                         float* __restrict__ bias,
                         const int* __restrict__ flags,
                         int nbT, int nbC, int E, int N){
    int b = blockIdx.x;
    int fF = flags[0];
    if (b < nbT){
        int t = b*256 + threadIdx.x;
        if (t >= N * 64) return;
        int n = t >> 6, l = t & 63;
        unsigned int xw, hw;
        if (fF){
            float2 xv = ((const float2*)X)[(size_t)n*64 + l];
            float2 hv = ((const float2*)H)[(size_t)n*64 + l];
            xw = ((unsigned int)f2bf(xv.y) << 16) | f2bf(xv.x);
            hw = ((unsigned int)f2bf(hv.y) << 16) | f2bf(hv.x);
        } else {
            xw = ((const unsigned int*)X)[(size_t)n*64 + l];
            hw = ((const unsigned int*)H)[(size_t)n*64 + l];
        }
        XHb32[(size_t)n*128 + l]      = xw;
        XHb32[(size_t)n*128 + 64 + l] = hw;
    } else if (b < nbT + nbC){
        int e = (b - nbT)*256 + threadIdx.x;
        if (e >= E) return;
        int fI = flags[1];
        int d = fI ? ei[2*(size_t)E + 2*(size_t)e] : ei[(size_t)E + e];
        if ((unsigned)d >= (unsigned)N) return;
        off[e] = atomicAdd(&cnt[d], 1);
        atomicAdd(&deg[d], ldsel(ew, e, fF));
    } else {
        int t = (b - nbT - nbC)*256 + threadIdx.x;
        if (t < 4*8*8*64*8){
            int j    =  t        & 7;
            int lane = (t >> 3)  & 63;
            int kb   = (t >> 9)  & 7;
            int ct   = (t >> 12) & 7;
            int g    = (t >> 15) & 3;
            int k   = kb*32 + (lane >> 4)*8 + j;
            int col = ct*16 + (lane & 15);
            const void* p; size_t idx;
            if (k < 128){ p = pa.Wx[g]; idx = (size_t)k*128 + col; }
            else        { p = pa.Wh[g]; idx = (size_t)(k-128)*128 + col; }
            unsigned short v;
            if (fF) v = f2bf(((const float*)p)[idx]);
            else    v = ((const unsigned short*)p)[idx];
            Bp[t] = v;
        }
        if (t < 512){
            int g = t >> 7, c = t & 127;
            bias[t] = ldsel(pa.bx[g], c, fF) + ldsel(pa.bh[g], c, fF);
        }
    }
}

// ---------------------------------------------------------------------------
// k_scanA: blocks [0,nbA): per-block sum of cnt -> bsum
//          blocks [nbA, nbA+nbD): dis = deg>0 ? rsqrt(deg) : 0
__global__ void k_scanA(const int* __restrict__ cnt, int* __restrict__ bsum,
                        const float* __restrict__ deg, float* __restrict__ dis,
                        int n, int nbA){
    if ((int)blockIdx.x < nbA){
        __shared__ int sh[256];
        int t = threadIdx.x, i = blockIdx.x * 256 + t;
        sh[t] = (i < n) ? cnt[i] : 0;
        __syncthreads();
        for (int o = 128; o > 0; o >>= 1){
            if (t < o) sh[t] += sh[t + o];
            __syncthreads();
        }
        if (t == 0) bsum[blockIdx.x] = sh[0];
    } else {
        int i = (blockIdx.x - nbA) * 256 + threadIdx.x;
        if (i < n){ float d = deg[i]; dis[i] = (d > 0.f) ? rsqrtf(d) : 0.f; }
    }
}

// k_scan2: rowstart = exclusive_scan(cnt); block offset recomputed from bsum
__global__ void k_scan2(const int* __restrict__ cnt, const int* __restrict__ bsum,
                        int* __restrict__ rowstart, int n){
    __shared__ int sh[256];
    int t = threadIdx.x, i = blockIdx.x * 256 + t;
    // block offset = sum of bsum[0..blockIdx)
    int base = 0;
    for (int j = t; j < (int)blockIdx.x; j += 256) base += bsum[j];
    sh[t] = base;
    __syncthreads();
    for (int o = 128; o > 0; o >>= 1){
        if (t < o) sh[t] += sh[t + o];
        __syncthreads();
    }
    int blockoff = sh[0];
    __syncthreads();
    // local inclusive scan
    int v = (i < n) ? cnt[i] : 0;
    sh[t] = v;
    __syncthreads();
    for (int o = 1; o < 256; o <<= 1){
        int u = (t >= o) ? sh[t - o] : 0;
        __syncthreads();
        sh[t] += u;
        __syncthreads();
    }
    int incl = sh[t];
    if (i < n)     rowstart[i] = blockoff + incl - v;
    if (i == n-1)  rowstart[n] = blockoff + incl;
}

// ---------------------------------------------------------------------------
// k_scatter: recs[rowstart[d]+off[e]] = {src, nrm}  (no atomics; nrm finalized)
__global__ void k_scatter(const int* __restrict__ ei, const void* __restrict__ ew,
                          const float* __restrict__ dis,
                          const int* __restrict__ rowstart, const int* __restrict__ off,
                          int2* __restrict__ recs, const int* __restrict__ flags,
                          int E, int N){
    int e = blockIdx.x * 256 + threadIdx.x;
    if (e >= E) return;
    int fF = flags[0], fI = flags[1];
    int s, d;
    if (fI){ s = ei[2*(size_t)e]; d = ei[2*(size_t)E + 2*(size_t)e]; }
    else   { s = ei[e];           d = ei[(size_t)E + e]; }
    if ((unsigned)d >= (unsigned)N) return;
    float w = 0.f; int ss = 0;
    if ((unsigned)s < (unsigned)N){ w = ldsel(ew, e, fF); ss = s; }
    float nrm = dis[ss] * w * dis[d];
    int2 r; r.x = ss; r.y = __float_as_int(nrm);
    recs[rowstart[d] + off[e]] = r;
}

// ---------------------------------------------------------------------------
// k_gather: 2 waves per node (wave = one 128-ch half: 0=X, 1=H).
// lane owns 2 channels (one uint of bf16x2). 4-edge unroll for MLP.
// Per-edge chain is just rec -> row (nrm precomputed in rec).
__global__ __launch_bounds__(256)
void k_gather(const int2* __restrict__ recs, const int* __restrict__ rowstart,
              const unsigned int* __restrict__ XHb32,
              unsigned int* __restrict__ AXH32, int N){
    int gw = (blockIdx.x * 256 + threadIdx.x) >> 6;
    int lane = threadIdx.x & 63;
    if (gw >= 2*N) return;
    int node = gw >> 1;
    int half = (gw & 1) * 64;
    int beg = rowstart[node], end = rowstart[node + 1];
    float a0 = 0.f, a1 = 0.f;
    int i = beg;
    for (; i + 3 < end; i += 4){
        int2 r0 = recs[i], r1 = recs[i+1], r2 = recs[i+2], r3 = recs[i+3];
        unsigned int v0 = XHb32[(size_t)r0.x*128 + half + lane];
        unsigned int v1 = XHb32[(size_t)r1.x*128 + half + lane];
        unsigned int v2 = XHb32[(size_t)r2.x*128 + half + lane];
        unsigned int v3 = XHb32[(size_t)r3.x*128 + half + lane];
        float n0 = __int_as_float(r0.y), n1 = __int_as_float(r1.y);
        float n2 = __int_as_float(r2.y), n3 = __int_as_float(r3.y);
        a0 += n0 * bf2f((unsigned short)(v0 & 0xffff));
        a1 += n0 * bf2f((unsigned short)(v0 >> 16));
        a0 += n1 * bf2f((unsigned short)(v1 & 0xffff));
        a1 += n1 * bf2f((unsigned short)(v1 >> 16));
        a0 += n2 * bf2f((unsigned short)(v2 & 0xffff));
        a1 += n2 * bf2f((unsigned short)(v2 >> 16));
        a0 += n3 * bf2f((unsigned short)(v3 & 0xffff));
        a1 += n3 * bf2f((unsigned short)(v3 >> 16));
    }
    for (; i < end; i++){
        int2 r0 = recs[i];
        float n0 = __int_as_float(r0.y);
        unsigned int v0 = XHb32[(size_t)r0.x*128 + half + lane];
        a0 += n0 * bf2f((unsigned short)(v0 & 0xffff));
        a1 += n0 * bf2f((unsigned short)(v0 >> 16));
    }
    AXH32[(size_t)node*128 + half + lane] = ((unsigned int)f2bf(a1) << 16) | f2bf(a0);
}

// ---------------------------------------------------------------------------
struct EpiArgs {
    const void *C, *wci, *wcf, *wco, *bi, *bff, *bc, *bo;
};

// Fused GEMM + LSTM epilogue. Block = 4 waves; 32 nodes (2 M-tiles sharing
// each B-fragment); wave g = gate g. A-frags loaded directly from AXH.
__global__ __launch_bounds__(256)
void k_gemm(const unsigned short* __restrict__ AXH,
            const unsigned short* __restrict__ Bp, const float* __restrict__ bias,
            EpiArgs ea, void* __restrict__ outp, const int* __restrict__ flags, int N){
    __shared__ float pre[4][16][132];

    int tid  = threadIdx.x;
    int wave = tid >> 6, lane = tid & 63;
    int node0 = blockIdx.x * 32;
    int fF = flags[0];

    f4v acc[2][8];
#pragma unroll
    for (int m = 0; m < 2; m++)
#pragma unroll
        for (int ct = 0; ct < 8; ct++) acc[m][ct] = (f4v){0.f,0.f,0.f,0.f};

    const int g = wave;
    const unsigned short* abase0 = AXH + (size_t)(node0      + (lane & 15))*256 + (lane >> 4)*8;
    const unsigned short* abase1 = AXH + (size_t)(node0 + 16 + (lane & 15))*256 + (lane >> 4)*8;
#pragma unroll
    for (int kb = 0; kb < 8; kb++){
        s8v af0 = *(const s8v*)(abase0 + kb*32);
        s8v af1 = *(const s8v*)(abase1 + kb*32);
        const unsigned short* bbase = Bp + g*32768 + kb*512 + lane*8;
#pragma unroll
        for (int ct = 0; ct < 8; ct++){
            s8v bfrag = *(const s8v*)(bbase + ct*4096);
            acc[0][ct] = __builtin_amdgcn_mfma_f32_16x16x32_bf16(af0, bfrag, acc[0][ct], 0, 0, 0);
            acc[1][ct] = __builtin_amdgcn_mfma_f32_16x16x32_bf16(af1, bfrag, acc[1][ct], 0, 0, 0);
        }
    }

    // D layout: col = lane&15, row = (lane>>4)*4 + r
    int q = lane >> 4, cl = lane & 15;
    for (int m = 0; m < 2; m++){
        int nbase = node0 + m*16;
#pragma unroll
        for (int ct = 0; ct < 8; ct++){
            int col = ct*16 + cl;
            float bv = bias[g*128 + col];
#pragma unroll
            for (int r = 0; r < 4; r++)
                pre[g][q*4 + r][col] = acc[m][ct][r] + bv;
        }
        __syncthreads();

        for (int i = tid; i < 2048; i += 256){
            int nn = i >> 7, c = i & 127;
            if (nbase + nn >= N) break;
            size_t gidx = (size_t)(nbase+nn)*128 + c;
            float Cv  = ldsel(ea.C, gidx, fF);
            float pi  = pre[0][nn][c], pf = pre[1][nn][c];
            float pcv = pre[2][nn][c], po = pre[3][nn][c];
            float Iv = sigm(pi + ldsel(ea.wci, c, fF)*Cv + ldsel(ea.bi, c, fF));
            float Fv = sigm(pf + ldsel(ea.wcf, c, fF)*Cv + ldsel(ea.bff, c, fF));
            float Tv = tanhf(pcv + ldsel(ea.bc, c, fF));
            float Cn = Fv*Cv + Iv*Tv;
            float Ov = sigm(po + ldsel(ea.wco, c, fF)*Cn + ldsel(ea.bo, c, fF));
            float Hn = Ov * tanhf(Cn);
            if (fF){
                ((float*)outp)[gidx] = Hn;
                ((float*)outp)[(size_t)N*128 + gidx] = Cn;
            } else {
                ((unsigned short*)outp)[gidx] = f2bf(Hn);
                ((unsigned short*)outp)[(size_t)N*128 + gidx] = f2bf(Cn);
            }
        }
        __syncthreads();
    }
}

// ---------------------------------------------------------------------------
extern "C" void kernel_launch(void* const* d_in, const int* in_sizes, int n_in,
                              void* d_out, int out_size, void* d_ws, size_t ws_size,
                              hipStream_t stream){
    const void* X  = d_in[0];
    const int*  ei = (const int*)d_in[1];
    const void* ew = d_in[2];
    const void* H  = d_in[3];
    const void* C  = d_in[4];
    const int N = in_sizes[0] / 128;
    const int E = in_sizes[2];

    // workspace layout (bytes), peak ~66.6 MB:
    // [0,256K) cnt | [256K,512K) deg | [512K,768K) dis | [768K,1028K) rowstart
    // [1028K] bsum(1K) | [1032K] flags(8B)
    // [1.25M,1.5M) Bp | [1.5M] bias(2K)
    // [2M,8.4M) off (dead after k_scatter)
    // [2M,28M) AXH (aliases off; written by k_gather after scatter)
    // [28M,40.8M) recs | [41M,66.6M) XHb
    char* ws = (char*)d_ws;
    int*   cnt          = (int*)  (ws);
    float* deg          = (float*)(ws + ((size_t)256 << 10));
    float* dis          = (float*)(ws + ((size_t)512 << 10));
    int*   rowstart     = (int*)  (ws + ((size_t)768 << 10));
    int*   bsum         = (int*)  (ws + ((size_t)1028 << 10));
    int*   flags        = (int*)  (ws + ((size_t)1032 << 10));
    unsigned short* Bp  = (unsigned short*)(ws + ((size_t)1280 << 10));
    float* bias         = (float*)(ws + ((size_t)1536 << 10));
    int*   off          = (int*)  (ws + ((size_t)2 << 20));
    unsigned int* AXH32 = (unsigned int*)(ws + ((size_t)2 << 20));
    int2*  recs         = (int2*) (ws + ((size_t)28 << 20));
    unsigned int* XHb32 = (unsigned int*)(ws + ((size_t)41 << 20));

    hipMemsetAsync(ws, 0, (size_t)512 << 10, stream);   // cnt + deg
    k_detect<<<1, 256, 0, stream>>>((const unsigned short*)X, ei, flags);

    PackArgs pa;
    pa.Wx[0]=d_in[5];  pa.bx[0]=d_in[6];  pa.Wh[0]=d_in[7];  pa.bh[0]=d_in[8];
    pa.Wx[1]=d_in[9];  pa.bx[1]=d_in[10]; pa.Wh[1]=d_in[11]; pa.bh[1]=d_in[12];
    pa.Wx[2]=d_in[13]; pa.bx[2]=d_in[14]; pa.Wh[2]=d_in[15]; pa.bh[2]=d_in[16];
    pa.Wx[3]=d_in[17]; pa.bx[3]=d_in[18]; pa.Wh[3]=d_in[19]; pa.bh[3]=d_in[20];

    int nbT = (N*64 + 255)/256;
    int nbC = (E + 255)/256;
    k_fused1<<<nbT + nbC + 512, 256, 0, stream>>>(X, H, XHb32, ei, ew, cnt, deg, off,
                                                  pa, Bp, bias, flags, nbT, nbC, E, N);

    int nbA = (N + 255)/256;
    k_scanA<<<nbA + nbA, 256, 0, stream>>>(cnt, bsum, deg, dis, N, nbA);
    k_scan2<<<nbA, 256, 0, stream>>>(cnt, bsum, rowstart, N);

    k_scatter<<<(E + 255)/256, 256, 0, stream>>>(ei, ew, dis, rowstart, off,
                                                 recs, flags, E, N);
    k_gather<<<(2*N*64 + 255)/256, 256, 0, stream>>>(recs, rowstart, XHb32, AXH32, N);

    EpiArgs ea;
    ea.C   = C;
    ea.wci = d_in[21];
    ea.wcf = d_in[22];
    ea.wco = d_in[23];
    ea.bi  = d_in[24];
    ea.bff = d_in[25];
    ea.bc  = d_in[26];
    ea.bo  = d_in[27];
    k_gemm<<<(N + 31)/32, 256, 0, stream>>>((const unsigned short*)AXH32, Bp, bias,
                                            ea, d_out, flags, N);
}